// Round 2
// baseline (672.100 us; speedup 1.0000x reference)
//
#include <hip/hip_runtime.h>
#include <hip/hip_fp16.h>

#define S_DIM 2048
#define B_DIM 32
#define E_DIM 1024
#define A_DIM 1024
#define D_DIM 1024
#define M_DIM (S_DIM * B_DIM)  // 65536

typedef _Float16 f16x8 __attribute__((ext_vector_type(8)));
typedef _Float16 f16x4 __attribute__((ext_vector_type(4)));
typedef float f32x4 __attribute__((ext_vector_type(4)));

#define OFF_ENC 0ull
#define OFF_WT  134217728ull
#define OFF_DP  (OFF_WT + 2097152ull)
#define OFF_EN  (OFF_DP + 131072ull)

__device__ inline void load_lds16(const void* g, void* l) {
    __builtin_amdgcn_global_load_lds((const __attribute__((address_space(1))) void*)g,
                                     (__attribute__((address_space(3))) void*)l, 16, 0, 0);
}

__global__ void convert_enc_kernel(const float4* __restrict__ in, f16x4* __restrict__ out) {
    int idx = blockIdx.x * 256 + threadIdx.x;
    float4 f = in[idx];
    f16x4 o = { (_Float16)f.x, (_Float16)f.y, (_Float16)f.z, (_Float16)f.w };
    out[idx] = o;
}

__global__ void transpose_wenc_kernel(const float* __restrict__ W, _Float16* __restrict__ WT) {
    __shared__ _Float16 tile[32][33];
    int a0 = blockIdx.x * 32, e0 = blockIdx.y * 32;
    int tx = threadIdx.x & 31, ty = threadIdx.x >> 5;
    #pragma unroll
    for (int i = 0; i < 32; i += 8)
        tile[ty + i][tx] = (_Float16)W[(size_t)(e0 + ty + i) * A_DIM + a0 + tx];
    __syncthreads();
    #pragma unroll
    for (int i = 0; i < 32; i += 8)
        WT[(size_t)(a0 + ty + i) * E_DIM + e0 + tx] = tile[tx][ty + i];
}

__global__ void decproj_kernel(const float* __restrict__ dec, const float* __restrict__ Wd,
                               const float* __restrict__ bias, float* __restrict__ dp) {
    int a = blockIdx.x * 256 + threadIdx.x;
    int b = blockIdx.y;
    float acc = bias[a];
    const float* dr = dec + (size_t)b * D_DIM;
    const float* wcol = Wd + a;
    #pragma unroll 8
    for (int d = 0; d < D_DIM; ++d)
        acc += dr[d] * wcol[(size_t)d * A_DIM];
    dp[(size_t)b * A_DIM + a] = acc;
}

__global__ __launch_bounds__(256, 2)
void energy_gemm_kernel(const _Float16* __restrict__ Af, const _Float16* __restrict__ Bt,
                        const float* __restrict__ dp, const float* __restrict__ v,
                        float* __restrict__ energy) {
    __shared__ alignas(16) _Float16 Atile[128 * 32];
    __shared__ alignas(16) _Float16 Btile[128 * 32];

    const int tid = threadIdx.x;
    const int wid = tid >> 6;
    const int lane = tid & 63;
    const int quad = lane >> 4;
    const int l15 = lane & 15;
    const int m0 = blockIdx.y * 128;
    const int n0 = blockIdx.x * 128;
    const int wm = (wid & 1) * 64;
    const int wn = (wid >> 1) * 64;

    const int srow = wid * 16 + (lane >> 2);
    const int skel = (lane & 3) * 8;
    const _Float16* Ag0 = Af + (size_t)(m0 + srow) * E_DIM + skel;
    const _Float16* Ag1 = Af + (size_t)(m0 + 64 + srow) * E_DIM + skel;
    const _Float16* Bg0 = Bt + (size_t)(n0 + srow) * E_DIM + skel;
    const _Float16* Bg1 = Bt + (size_t)(n0 + 64 + srow) * E_DIM + skel;
    _Float16* Al0 = Atile + wid * 512;
    _Float16* Al1 = Atile + 2048 + wid * 512;
    _Float16* Bl0 = Btile + wid * 512;
    _Float16* Bl1 = Btile + 2048 + wid * 512;

    f32x4 acc[4][4] = {};

    for (int k0 = 0; k0 < E_DIM; k0 += 32) {
        __syncthreads();
        load_lds16(Ag0 + k0, Al0);
        load_lds16(Ag1 + k0, Al1);
        load_lds16(Bg0 + k0, Bl0);
        load_lds16(Bg1 + k0, Bl1);
        __syncthreads();

        f16x8 af[4], bfr[4];
        #pragma unroll
        for (int i = 0; i < 4; ++i)
            af[i] = *(const f16x8*)&Atile[(wm + i * 16 + l15) * 32 + quad * 8];
        #pragma unroll
        for (int j = 0; j < 4; ++j)
            bfr[j] = *(const f16x8*)&Btile[(wn + j * 16 + l15) * 32 + quad * 8];
        #pragma unroll
        for (int i = 0; i < 4; ++i)
            #pragma unroll
            for (int j = 0; j < 4; ++j)
                acc[i][j] = __builtin_amdgcn_mfma_f32_16x16x32_f16(af[i], bfr[j], acc[i][j], 0, 0, 0);
    }

    float vf[4];
    #pragma unroll
    for (int j = 0; j < 4; ++j) vf[j] = v[n0 + wn + j * 16 + l15];

    #pragma unroll
    for (int i = 0; i < 4; ++i) {
        #pragma unroll
        for (int r = 0; r < 4; ++r) {
            int m = m0 + wm + i * 16 + quad * 4 + r;
            int bidx = m & 31;
            float sum = 0.f;
            #pragma unroll
            for (int j = 0; j < 4; ++j) {
                int a = n0 + wn + j * 16 + l15;
                float x = acc[i][j][r] + dp[bidx * A_DIM + a];
                float ex = __expf(2.f * x);
                float t = 1.f - 2.f * __builtin_amdgcn_rcpf(ex + 1.f);
                sum += t * vf[j];
            }
            sum += __shfl_xor(sum, 1);
            sum += __shfl_xor(sum, 2);
            sum += __shfl_xor(sum, 4);
            sum += __shfl_xor(sum, 8);
            if (l15 == 0) atomicAdd(&energy[m], sum);
        }
    }
}

__global__ void scan_alpha_kernel(const float* __restrict__ energy, float* __restrict__ alpha) {
    __shared__ float sc[256];
    __shared__ float red[256];
    const int b = blockIdx.x;
    const int t = threadIdx.x;
    float p[8], q[8];
    float prod = 1.f;
    #pragma unroll
    for (int k = 0; k < 8; ++k) {
        int s = t * 8 + k;
        float x = energy[s * B_DIM + b];
        p[k] = __builtin_amdgcn_rcpf(1.f + __expf(-x));
        q[k] = __builtin_amdgcn_rcpf(1.f + __expf(x));
        prod *= q[k];
    }
    sc[t] = prod;
    __syncthreads();
    for (int off = 1; off < 256; off <<= 1) {
        float mine = sc[t];
        float other = (t >= off) ? sc[t - off] : 1.f;
        __syncthreads();
        sc[t] = mine * other;
        __syncthreads();
    }
    float run = (t > 0) ? sc[t - 1] : 1.f;
    float lsum = 0.f;
    #pragma unroll
    for (int k = 0; k < 8; ++k) {
        int s = t * 8 + k;
        float al = p[k] * run;
        run *= q[k];
        if (s < S_DIM - 1) { alpha[s * B_DIM + b] = al; lsum += al; }
    }
    red[t] = lsum;
    __syncthreads();
    for (int off = 128; off > 0; off >>= 1) {
        if (t < off) red[t] += red[t + off];
        __syncthreads();
    }
    if (t == 0) {
        float tot = fminf(fmaxf(red[0], 0.f), 1.f);
        alpha[(S_DIM - 1) * B_DIM + b] = 1.f - tot;
    }
}

__global__ void wc_kernel(const _Float16* __restrict__ enc, const float* __restrict__ alpha,
                          float* __restrict__ wc) {
    int e0 = (blockIdx.x * 256 + threadIdx.x) * 2;
    int b = blockIdx.y;
    int s0 = blockIdx.z * 128;
    float a0 = 0.f, a1 = 0.f;
    for (int s = s0; s < s0 + 128; ++s) {
        float al = alpha[s * B_DIM + b];
        const _Float16* row = enc + ((size_t)s * B_DIM + b) * E_DIM + e0;
        a0 += al * (float)row[0];
        a1 += al * (float)row[1];
    }
    atomicAdd(&wc[b * E_DIM + e0], a0);
    atomicAdd(&wc[b * E_DIM + e0 + 1], a1);
}

extern "C" void kernel_launch(void* const* d_in, const int* in_sizes, int n_in,
                              void* d_out, int out_size, void* d_ws, size_t ws_size,
                              hipStream_t stream) {
    const float* dec   = (const float*)d_in[0];
    const float* enc   = (const float*)d_in[1];
    const float* noise = (const float*)d_in[2];
    const float* Wd    = (const float*)d_in[3];
    const float* We    = (const float*)d_in[4];
    const float* bias  = (const float*)d_in[5];
    const float* v     = (const float*)d_in[6];

    char* ws = (char*)d_ws;
    _Float16* encf = (_Float16*)(ws + OFF_ENC);
    _Float16* wtf  = (_Float16*)(ws + OFF_WT);
    float* dp      = (float*)(ws + OFF_DP);
    float* energy  = (float*)(ws + OFF_EN);

    float* wc    = (float*)d_out;
    float* alpha = (float*)d_out + B_DIM * E_DIM;

    (void)hipMemsetAsync(wc, 0, B_DIM * E_DIM * sizeof(float), stream);
    (void)hipMemcpyAsync(energy, noise, M_DIM * sizeof(float), hipMemcpyDeviceToDevice, stream);

    convert_enc_kernel<<<dim3(M_DIM * E_DIM / 4 / 256), 256, 0, stream>>>((const float4*)enc, (f16x4*)encf);
    transpose_wenc_kernel<<<dim3(32, 32), 256, 0, stream>>>(We, wtf);
    decproj_kernel<<<dim3(4, 32), 256, 0, stream>>>(dec, Wd, bias, dp);
    energy_gemm_kernel<<<dim3(8, 512), 256, 0, stream>>>(encf, wtf, dp, v, energy);
    scan_alpha_kernel<<<dim3(32), 256, 0, stream>>>(energy, alpha);
    wc_kernel<<<dim3(2, 32, 16), 256, 0, stream>>>(encf, alpha, wc);
}

// Round 3
// 664.566 us; speedup vs baseline: 1.0113x; 1.0113x over previous
//
#include <hip/hip_runtime.h>
#include <hip/hip_fp16.h>

#define S_DIM 2048
#define B_DIM 32
#define E_DIM 1024
#define A_DIM 1024
#define D_DIM 1024
#define M_DIM (S_DIM * B_DIM)  // 65536

typedef _Float16 f16x8 __attribute__((ext_vector_type(8)));
typedef _Float16 f16x4 __attribute__((ext_vector_type(4)));
typedef float f32x4 __attribute__((ext_vector_type(4)));

#define OFF_ENC 0ull
#define OFF_WT  134217728ull
#define OFF_DP  (OFF_WT + 2097152ull)
#define OFF_EN  (OFF_DP + 131072ull)

__device__ inline void load_lds16(const void* g, void* l) {
    __builtin_amdgcn_global_load_lds((const __attribute__((address_space(1))) void*)g,
                                     (__attribute__((address_space(3))) void*)l, 16, 0, 0);
}

__global__ void convert_enc_kernel(const float4* __restrict__ in, f16x4* __restrict__ out) {
    int idx = blockIdx.x * 256 + threadIdx.x;
    float4 f = in[idx];
    f16x4 o = { (_Float16)f.x, (_Float16)f.y, (_Float16)f.z, (_Float16)f.w };
    out[idx] = o;
}

__global__ void transpose_wenc_kernel(const float* __restrict__ W, _Float16* __restrict__ WT) {
    __shared__ _Float16 tile[32][33];
    int a0 = blockIdx.x * 32, e0 = blockIdx.y * 32;
    int tx = threadIdx.x & 31, ty = threadIdx.x >> 5;
    #pragma unroll
    for (int i = 0; i < 32; i += 8)
        tile[ty + i][tx] = (_Float16)W[(size_t)(e0 + ty + i) * A_DIM + a0 + tx];
    __syncthreads();
    #pragma unroll
    for (int i = 0; i < 32; i += 8)
        WT[(size_t)(a0 + ty + i) * E_DIM + e0 + tx] = tile[tx][ty + i];
}

__global__ void decproj_kernel(const float* __restrict__ dec, const float* __restrict__ Wd,
                               const float* __restrict__ bias, float* __restrict__ dp) {
    int a = blockIdx.x * 256 + threadIdx.x;
    int b = blockIdx.y;
    float acc = bias[a];
    const float* dr = dec + (size_t)b * D_DIM;
    const float* wcol = Wd + a;
    #pragma unroll 8
    for (int d = 0; d < D_DIM; ++d)
        acc += dr[d] * wcol[(size_t)d * A_DIM];
    dp[(size_t)b * A_DIM + a] = acc;
}

// 128x128 tile, BK=32, f16 MFMA. XCD swizzle for A reuse, XOR-swizzled LDS
// chunk positions to kill the 8-way ds_read_b128 bank conflicts.
// energy laid out [B][S] (zero-initialized; noise added in scan kernel).
__global__ __launch_bounds__(256, 2)
void energy_gemm_kernel(const _Float16* __restrict__ Af, const _Float16* __restrict__ Bt,
                        const float* __restrict__ dp, const float* __restrict__ v,
                        float* __restrict__ energy) {
    __shared__ alignas(16) _Float16 Atile[128 * 32];
    __shared__ alignas(16) _Float16 Btile[128 * 32];

    const int tid = threadIdx.x;
    const int wid = tid >> 6;
    const int lane = tid & 63;
    const int quad = lane >> 4;
    const int l15 = lane & 15;

    // XCD-aware swizzle: flat id -> xcd = bid%8 owns m-tiles [64*xcd, 64*xcd+64)
    // with all 8 n-tiles -> A-rows fetched ~once per XCD L2.
    const int bid = blockIdx.x + (int)(gridDim.x * blockIdx.y);  // 0..4095
    const int xcd = bid & 7;
    const int local = bid >> 3;               // 0..511
    const int m0 = (xcd * 64 + (local >> 3)) * 128;
    const int n0 = (local & 7) * 128;

    const int wm = (wid & 1) * 64;
    const int wn = (wid >> 1) * 64;

    // staging: lane l -> LDS row l>>2, position l&3 (fixed by global_load_lds).
    // fetch the global k-chunk that belongs at this position under the XOR perm:
    // position p of row r holds logical chunk p ^ ((r>>1)&3).
    const int srow = wid * 16 + (lane >> 2);
    const int skel = (((lane & 3) ^ ((lane >> 3) & 3)) * 8);
    const _Float16* Ag0 = Af + (size_t)(m0 + srow) * E_DIM + skel;
    const _Float16* Ag1 = Af + (size_t)(m0 + 64 + srow) * E_DIM + skel;
    const _Float16* Bg0 = Bt + (size_t)(n0 + srow) * E_DIM + skel;
    const _Float16* Bg1 = Bt + (size_t)(n0 + 64 + srow) * E_DIM + skel;
    _Float16* Al0 = Atile + wid * 512;
    _Float16* Al1 = Atile + 2048 + wid * 512;
    _Float16* Bl0 = Btile + wid * 512;
    _Float16* Bl1 = Btile + 2048 + wid * 512;

    // reader: logical chunk `quad` of row (..+l15) sits at position quad^((l15>>1)&3)
    const int swz = (quad ^ ((l15 >> 1) & 3)) * 8;

    f32x4 acc[4][4] = {};

    for (int k0 = 0; k0 < E_DIM; k0 += 32) {
        __syncthreads();
        load_lds16(Ag0 + k0, Al0);
        load_lds16(Ag1 + k0, Al1);
        load_lds16(Bg0 + k0, Bl0);
        load_lds16(Bg1 + k0, Bl1);
        __syncthreads();

        f16x8 af[4], bfr[4];
        #pragma unroll
        for (int i = 0; i < 4; ++i)
            af[i] = *(const f16x8*)&Atile[(wm + i * 16 + l15) * 32 + swz];
        #pragma unroll
        for (int j = 0; j < 4; ++j)
            bfr[j] = *(const f16x8*)&Btile[(wn + j * 16 + l15) * 32 + swz];
        #pragma unroll
        for (int i = 0; i < 4; ++i)
            #pragma unroll
            for (int j = 0; j < 4; ++j)
                acc[i][j] = __builtin_amdgcn_mfma_f32_16x16x32_f16(af[i], bfr[j], acc[i][j], 0, 0, 0);
    }

    float vf[4];
    #pragma unroll
    for (int j = 0; j < 4; ++j) vf[j] = v[n0 + wn + j * 16 + l15];

    #pragma unroll
    for (int i = 0; i < 4; ++i) {
        #pragma unroll
        for (int r = 0; r < 4; ++r) {
            int m = m0 + wm + i * 16 + quad * 4 + r;   // m = s*32 + b
            int bidx = m & 31;
            float sum = 0.f;
            #pragma unroll
            for (int j = 0; j < 4; ++j) {
                int a = n0 + wn + j * 16 + l15;
                float x = acc[i][j][r] + dp[bidx * A_DIM + a];
                float ex = __expf(2.f * x);
                float t = 1.f - 2.f * __builtin_amdgcn_rcpf(ex + 1.f);
                sum += t * vf[j];
            }
            sum += __shfl_xor(sum, 1);
            sum += __shfl_xor(sum, 2);
            sum += __shfl_xor(sum, 4);
            sum += __shfl_xor(sum, 8);
            if (l15 == 0) atomicAdd(&energy[bidx * S_DIM + (m >> 5)], sum);
        }
    }
}

// one block per b column; energy [B][S] coalesced; noise [S][B] added here
__global__ void scan_alpha_kernel(const float* __restrict__ energy, const float* __restrict__ noise,
                                  float* __restrict__ alpha) {
    __shared__ float sc[256];
    __shared__ float red[256];
    const int b = blockIdx.x;
    const int t = threadIdx.x;
    float p[8], q[8];
    float prod = 1.f;
    #pragma unroll
    for (int k = 0; k < 8; ++k) {
        int s = t * 8 + k;
        float x = energy[b * S_DIM + s] + noise[s * B_DIM + b];
        p[k] = __builtin_amdgcn_rcpf(1.f + __expf(-x));
        q[k] = __builtin_amdgcn_rcpf(1.f + __expf(x));
        prod *= q[k];
    }
    sc[t] = prod;
    __syncthreads();
    for (int off = 1; off < 256; off <<= 1) {
        float mine = sc[t];
        float other = (t >= off) ? sc[t - off] : 1.f;
        __syncthreads();
        sc[t] = mine * other;
        __syncthreads();
    }
    float run = (t > 0) ? sc[t - 1] : 1.f;
    float lsum = 0.f;
    #pragma unroll
    for (int k = 0; k < 8; ++k) {
        int s = t * 8 + k;
        float al = p[k] * run;
        run *= q[k];
        if (s < S_DIM - 1) { alpha[s * B_DIM + b] = al; lsum += al; }
    }
    red[t] = lsum;
    __syncthreads();
    for (int off = 128; off > 0; off >>= 1) {
        if (t < off) red[t] += red[t + off];
        __syncthreads();
    }
    if (t == 0) {
        float tot = fminf(fmaxf(red[0], 0.f), 1.f);
        alpha[(S_DIM - 1) * B_DIM + b] = 1.f - tot;
    }
}

// grid (16 s-chunks, 32 b), block 256: thread t covers e = (t&127)*8..+7 (16B loads),
// halves t<128 / t>=128 split the s range, LDS-reduce, one atomic set per block.
__global__ void wc_kernel(const _Float16* __restrict__ enc, const float* __restrict__ alpha,
                          float* __restrict__ wc) {
    __shared__ float red[128][8];
    const int b = blockIdx.y;
    const int t = threadIdx.x;
    const int e0 = (t & 127) * 8;
    const int half = t >> 7;
    int s = blockIdx.x * 128 + half;
    float acc[8] = {};
    for (int i = 0; i < 64; ++i, s += 2) {
        float al = alpha[s * B_DIM + b];
        f16x8 r = *(const f16x8*)&enc[((size_t)s * B_DIM + b) * E_DIM + e0];
        #pragma unroll
        for (int k = 0; k < 8; ++k) acc[k] += al * (float)r[k];
    }
    if (half) {
        #pragma unroll
        for (int k = 0; k < 8; ++k) red[t - 128][k] = acc[k];
    }
    __syncthreads();
    if (!half) {
        #pragma unroll
        for (int k = 0; k < 8; ++k)
            atomicAdd(&wc[b * E_DIM + e0 + k], acc[k] + red[t][k]);
    }
}

extern "C" void kernel_launch(void* const* d_in, const int* in_sizes, int n_in,
                              void* d_out, int out_size, void* d_ws, size_t ws_size,
                              hipStream_t stream) {
    const float* dec   = (const float*)d_in[0];
    const float* enc   = (const float*)d_in[1];
    const float* noise = (const float*)d_in[2];
    const float* Wd    = (const float*)d_in[3];
    const float* We    = (const float*)d_in[4];
    const float* bias  = (const float*)d_in[5];
    const float* v     = (const float*)d_in[6];

    char* ws = (char*)d_ws;
    _Float16* encf = (_Float16*)(ws + OFF_ENC);
    _Float16* wtf  = (_Float16*)(ws + OFF_WT);
    float* dp      = (float*)(ws + OFF_DP);
    float* energy  = (float*)(ws + OFF_EN);

    float* wc    = (float*)d_out;
    float* alpha = (float*)d_out + B_DIM * E_DIM;

    (void)hipMemsetAsync(wc, 0, B_DIM * E_DIM * sizeof(float), stream);
    (void)hipMemsetAsync(energy, 0, M_DIM * sizeof(float), stream);

    convert_enc_kernel<<<dim3(M_DIM * E_DIM / 4 / 256), 256, 0, stream>>>((const float4*)enc, (f16x4*)encf);
    transpose_wenc_kernel<<<dim3(32, 32), 256, 0, stream>>>(We, wtf);
    decproj_kernel<<<dim3(4, 32), 256, 0, stream>>>(dec, Wd, bias, dp);
    energy_gemm_kernel<<<dim3(8, 512), 256, 0, stream>>>(encf, wtf, dp, v, energy);
    scan_alpha_kernel<<<dim3(32), 256, 0, stream>>>(energy, noise, alpha);
    wc_kernel<<<dim3(16, 32), 256, 0, stream>>>(encf, alpha, wc);
}